// Round 1
// baseline (360.381 us; speedup 1.0000x reference)
//
#include <hip/hip_runtime.h>

typedef short bf16x8 __attribute__((ext_vector_type(8)));
typedef float f32x4 __attribute__((ext_vector_type(4)));
typedef unsigned short us4 __attribute__((ext_vector_type(4)));

#define S_LEN 2048
#define HIDD 1024
#define NH 16
#define HD 64
#define NEGV -1e9f

#define BM 128
#define BN 128
#define BK 64
#define LDSS 72  // 64 + 8 pad: row stride 144B -> 2-way bank alias (free), keeps 16B align

static __device__ __forceinline__ unsigned short f2bf(float f) {
  union { float f; unsigned u; } v; v.f = f;
  unsigned r = v.u + 0x7FFFu + ((v.u >> 16) & 1u);  // RNE
  return (unsigned short)(r >> 16);
}

// ---------------- f32 -> bf16 conversion for hs + 4 weights ----------------
__global__ __launch_bounds__(256) void cvt5_kernel(
    const float* __restrict__ s0, const float* __restrict__ s1, const float* __restrict__ s2,
    const float* __restrict__ s3, const float* __restrict__ s4,
    unsigned short* __restrict__ d0, unsigned short* __restrict__ d1,
    unsigned short* __restrict__ d2, unsigned short* __restrict__ d3,
    unsigned short* __restrict__ d4) {
  const float* s; unsigned short* d; int n4;
  switch (blockIdx.y) {
    case 0: s = s0; d = d0; n4 = (2 * S_LEN * HIDD) / 4; break;
    case 1: s = s1; d = d1; n4 = (HIDD * HIDD) / 4; break;
    case 2: s = s2; d = d2; n4 = (HIDD * HIDD) / 4; break;
    case 3: s = s3; d = d3; n4 = (HIDD * HIDD) / 4; break;
    default: s = s4; d = d4; n4 = (HIDD * HIDD) / 4; break;
  }
  for (int i = blockIdx.x * blockDim.x + threadIdx.x; i < n4;
       i += gridDim.x * blockDim.x) {
    float4 v = ((const float4*)s)[i];
    us4 o;
    o.x = f2bf(v.x); o.y = f2bf(v.y); o.z = f2bf(v.z); o.w = f2bf(v.w);
    ((us4*)d)[i] = o;
  }
}

// ---------------- shared GEMM core: C = A[M,K] * W[N,K]^T ----------------
// 128x128 tile, BK=64, 4 waves (2x2), each wave 64x64 = 4x4 frags of 16x16x32.
static __device__ __forceinline__ void gemm_core(
    const unsigned short* __restrict__ A, const unsigned short* __restrict__ W,
    int bm0, int bn0, unsigned short* As, unsigned short* Bs, f32x4 (&acc)[4][4]) {
  const int tid = threadIdx.x;
  const int lane = tid & 63;
  const int wid = tid >> 6;
  const int wr = wid >> 1, wc = wid & 1;
  const int l15 = lane & 15, g = lane >> 4;

  for (int k0 = 0; k0 < HIDD; k0 += BK) {
    __syncthreads();
#pragma unroll
    for (int it = 0; it < 4; ++it) {
      int id = tid + it * 256;          // 0..1023
      int row = id >> 3;                // 0..127
      int col = (id & 7) * 8;           // 0..56
      *(bf16x8*)&As[row * LDSS + col] =
          *(const bf16x8*)&A[(size_t)(bm0 + row) * HIDD + k0 + col];
      *(bf16x8*)&Bs[row * LDSS + col] =
          *(const bf16x8*)&W[(size_t)(bn0 + row) * HIDD + k0 + col];
    }
    __syncthreads();
#pragma unroll
    for (int kk = 0; kk < 2; ++kk) {
      bf16x8 af[4], bfr[4];
#pragma unroll
      for (int m = 0; m < 4; ++m)
        af[m] = *(const bf16x8*)&As[(wr * 64 + m * 16 + l15) * LDSS + kk * 32 + g * 8];
#pragma unroll
      for (int n = 0; n < 4; ++n)
        bfr[n] = *(const bf16x8*)&Bs[(wc * 64 + n * 16 + l15) * LDSS + kk * 32 + g * 8];
#pragma unroll
      for (int m = 0; m < 4; ++m)
#pragma unroll
        for (int n = 0; n < 4; ++n)
          acc[m][n] = __builtin_amdgcn_mfma_f32_16x16x32_bf16(af[m], bfr[n], acc[m][n], 0, 0, 0);
    }
  }
}

// ---------------- QKV projection (z=0:Q scaled, 1:K, 2:V->VT) ----------------
__global__ __launch_bounds__(256) void gemm_qkv(
    const unsigned short* __restrict__ hs,
    const unsigned short* __restrict__ Wq, const unsigned short* __restrict__ Wk,
    const unsigned short* __restrict__ Wv,
    const float* __restrict__ bq, const float* __restrict__ bk, const float* __restrict__ bv,
    unsigned short* __restrict__ Qs, unsigned short* __restrict__ Kb,
    unsigned short* __restrict__ VT) {
  __shared__ unsigned short As[BM * LDSS];
  __shared__ unsigned short Bs[BN * LDSS];
  const int z = blockIdx.z;
  const unsigned short* W = (z == 0) ? Wq : ((z == 1) ? Wk : Wv);
  const float* bias = (z == 0) ? bq : ((z == 1) ? bk : bv);

  f32x4 acc[4][4];
#pragma unroll
  for (int m = 0; m < 4; ++m)
#pragma unroll
    for (int n = 0; n < 4; ++n) acc[m][n] = (f32x4){0.f, 0.f, 0.f, 0.f};

  const int bm0 = blockIdx.x * BM, bn0 = blockIdx.y * BN;
  gemm_core(hs, W, bm0, bn0, As, Bs, acc);

  const int lane = threadIdx.x & 63;
  const int wid = threadIdx.x >> 6;
  const int wr = wid >> 1, wc = wid & 1;
  const int l15 = lane & 15, g = lane >> 4;

#pragma unroll
  for (int m = 0; m < 4; ++m) {
#pragma unroll
    for (int n = 0; n < 4; ++n) {
      int grow0 = bm0 + wr * 64 + m * 16 + g * 4;
      int gcol = bn0 + wc * 64 + n * 16 + l15;
      float bv_ = bias[gcol];
      if (z == 0) {
#pragma unroll
        for (int i = 0; i < 4; ++i)
          Qs[(size_t)(grow0 + i) * HIDD + gcol] = f2bf((acc[m][n][i] + bv_) * 0.125f);
      } else if (z == 1) {
#pragma unroll
        for (int i = 0; i < 4; ++i)
          Kb[(size_t)(grow0 + i) * HIDD + gcol] = f2bf(acc[m][n][i] + bv_);
      } else {
        // VT[b][h][d][s]: 4 consecutive s -> one 8B store
        int b = grow0 >> 11, s = grow0 & 2047;
        int h = gcol >> 6, d = gcol & 63;
        us4 pk;
#pragma unroll
        for (int i = 0; i < 4; ++i) pk[i] = f2bf(acc[m][n][i] + bv_);
        *(us4*)&VT[((size_t)(b * NH + h) * HD + d) * S_LEN + s] = pk;
      }
    }
  }
}

// ---------------- output projection: f32 result ----------------
__global__ __launch_bounds__(256) void gemm_o(
    const unsigned short* __restrict__ ctx, const unsigned short* __restrict__ Wo,
    const float* __restrict__ bo, float* __restrict__ out) {
  __shared__ unsigned short As[BM * LDSS];
  __shared__ unsigned short Bs[BN * LDSS];
  f32x4 acc[4][4];
#pragma unroll
  for (int m = 0; m < 4; ++m)
#pragma unroll
    for (int n = 0; n < 4; ++n) acc[m][n] = (f32x4){0.f, 0.f, 0.f, 0.f};

  const int bm0 = blockIdx.x * BM, bn0 = blockIdx.y * BN;
  gemm_core(ctx, Wo, bm0, bn0, As, Bs, acc);

  const int lane = threadIdx.x & 63;
  const int wid = threadIdx.x >> 6;
  const int wr = wid >> 1, wc = wid & 1;
  const int l15 = lane & 15, g = lane >> 4;
#pragma unroll
  for (int m = 0; m < 4; ++m) {
#pragma unroll
    for (int n = 0; n < 4; ++n) {
      int grow0 = bm0 + wr * 64 + m * 16 + g * 4;
      int gcol = bn0 + wc * 64 + n * 16 + l15;
      float bv_ = bo[gcol];
#pragma unroll
      for (int i = 0; i < 4; ++i)
        out[(size_t)(grow0 + i) * HIDD + gcol] = acc[m][n][i] + bv_;
    }
  }
}

// ---------------- flash attention, swapped-operand, per-wave q-tile of 16 ----------------
// grid: (x = b*h 32, y = qtile/4 32), block 256 (4 waves, each one q-tile)
__global__ __launch_bounds__(256) void attn_kernel(
    const unsigned short* __restrict__ Qs, const unsigned short* __restrict__ Kb,
    const unsigned short* __restrict__ VT, const unsigned char* __restrict__ mask8,
    unsigned short* __restrict__ ctx) {
  __shared__ unsigned short Pl[4][16][40];  // per-wave P[qrow][kcol], stride 40 (pad)

  const int wid = threadIdx.x >> 6, lane = threadIdx.x & 63;
  const int l15 = lane & 15, g = lane >> 4;
  const int bh = blockIdx.x;
  const int qt = blockIdx.y * 4 + wid;   // 0..127
  const int b = bh >> 4, h = bh & 15;
  const int q0 = qt * 16;

  const bool bytemode = (mask8[1] != 0);  // bool-as-u8 vs 4-byte elems
  const unsigned char* mrow8 = mask8 + (size_t)(q0 + l15) * S_LEN;
  const int* mrow32 = (const int*)mask8 + (size_t)(q0 + l15) * S_LEN;

  // Q B-frags (col = qrow = l15, k = d contiguous), Q pre-scaled by 1/8
  const unsigned short* Qrow = Qs + (size_t)(b * S_LEN + q0 + l15) * HIDD + h * HD;
  bf16x8 qf0 = *(const bf16x8*)(Qrow + g * 8);
  bf16x8 qf1 = *(const bf16x8*)(Qrow + 32 + g * 8);

  const unsigned short* Kbh = Kb + (size_t)b * S_LEN * HIDD + h * HD;
  const unsigned short* VTbh = VT + (size_t)(b * NH + h) * HD * S_LEN;

  float m_run = -1e30f, l_run = 0.f;
  f32x4 oacc[4];
#pragma unroll
  for (int dc = 0; dc < 4; ++dc) oacc[dc] = (f32x4){0.f, 0.f, 0.f, 0.f};

  for (int kv0 = 0; kv0 < S_LEN; kv0 += 32) {
    // S^T = K * Q^T : lane holds S[kv0 + g*4+i][q0+l15] (tile a) and +16 (tile b)
    const unsigned short* Ka = Kbh + (size_t)(kv0 + l15) * HIDD;
    const unsigned short* Kc = Kbh + (size_t)(kv0 + 16 + l15) * HIDD;
    f32x4 sa = (f32x4){0.f, 0.f, 0.f, 0.f};
    f32x4 sb = (f32x4){0.f, 0.f, 0.f, 0.f};
    sa = __builtin_amdgcn_mfma_f32_16x16x32_bf16(*(const bf16x8*)(Ka + g * 8), qf0, sa, 0, 0, 0);
    sa = __builtin_amdgcn_mfma_f32_16x16x32_bf16(*(const bf16x8*)(Ka + 32 + g * 8), qf1, sa, 0, 0, 0);
    sb = __builtin_amdgcn_mfma_f32_16x16x32_bf16(*(const bf16x8*)(Kc + g * 8), qf0, sb, 0, 0, 0);
    sb = __builtin_amdgcn_mfma_f32_16x16x32_bf16(*(const bf16x8*)(Kc + 32 + g * 8), qf1, sb, 0, 0, 0);

    float s[8];
    if (bytemode) {
      unsigned ma = *(const unsigned*)(mrow8 + kv0 + g * 4);
      unsigned mb = *(const unsigned*)(mrow8 + kv0 + 16 + g * 4);
#pragma unroll
      for (int i = 0; i < 4; ++i) {
        s[i]     = ((ma >> (8 * i)) & 255u) ? sa[i] : NEGV;
        s[4 + i] = ((mb >> (8 * i)) & 255u) ? sb[i] : NEGV;
      }
    } else {
      int4 ma = *(const int4*)(mrow32 + kv0 + g * 4);
      int4 mb = *(const int4*)(mrow32 + kv0 + 16 + g * 4);
      s[0] = ma.x ? sa[0] : NEGV; s[1] = ma.y ? sa[1] : NEGV;
      s[2] = ma.z ? sa[2] : NEGV; s[3] = ma.w ? sa[3] : NEGV;
      s[4] = mb.x ? sb[0] : NEGV; s[5] = mb.y ? sb[1] : NEGV;
      s[6] = mb.z ? sb[2] : NEGV; s[7] = mb.w ? sb[3] : NEGV;
    }

    // online softmax per q-row (= per lane column, state replicated over g)
    float pmax = s[0];
#pragma unroll
    for (int j = 1; j < 8; ++j) pmax = fmaxf(pmax, s[j]);
    pmax = fmaxf(pmax, __shfl_xor(pmax, 16));
    pmax = fmaxf(pmax, __shfl_xor(pmax, 32));
    float m_new = fmaxf(m_run, pmax);
    float corr = __expf(m_run - m_new);
    float p[8], lsum = 0.f;
#pragma unroll
    for (int j = 0; j < 8; ++j) { p[j] = __expf(s[j] - m_new); lsum += p[j]; }
    lsum += __shfl_xor(lsum, 16);
    lsum += __shfl_xor(lsum, 32);
    l_run = l_run * corr + lsum;
    m_run = m_new;
#pragma unroll
    for (int dc = 0; dc < 4; ++dc) oacc[dc] *= corr;

    // P -> LDS [qrow][kcol] (two 8B writes), reread as PV B-frag (16B)
    us4 pka, pkb;
#pragma unroll
    for (int i = 0; i < 4; ++i) { pka[i] = f2bf(p[i]); pkb[i] = f2bf(p[4 + i]); }
    *(us4*)&Pl[wid][l15][g * 4] = pka;
    *(us4*)&Pl[wid][l15][16 + g * 4] = pkb;
    bf16x8 pb_ = *(const bf16x8*)&Pl[wid][l15][g * 8];

    // O^T += VT_tile * P   (A rows = d, k = kv contiguous in VT)
#pragma unroll
    for (int dc = 0; dc < 4; ++dc) {
      bf16x8 vf = *(const bf16x8*)(VTbh + (size_t)(dc * 16 + l15) * S_LEN + kv0 + g * 8);
      oacc[dc] = __builtin_amdgcn_mfma_f32_16x16x32_bf16(vf, pb_, oacc[dc], 0, 0, 0);
    }
  }

  float inv_l = 1.f / l_run;  // local window guarantees l >= 1
  unsigned short* crow = ctx + (size_t)(b * S_LEN + q0 + l15) * HIDD + h * HD;
#pragma unroll
  for (int dc = 0; dc < 4; ++dc) {
    us4 o;
#pragma unroll
    for (int i = 0; i < 4; ++i) o[i] = f2bf(oacc[dc][i] * inv_l);
    *(us4*)&crow[dc * 16 + g * 4] = o;
  }
}

extern "C" void kernel_launch(void* const* d_in, const int* in_sizes, int n_in,
                              void* d_out, int out_size, void* d_ws, size_t ws_size,
                              hipStream_t stream) {
  const float* hs = (const float*)d_in[0];
  const float* Wq = (const float*)d_in[1];
  const float* bq = (const float*)d_in[2];
  const float* Wk = (const float*)d_in[3];
  const float* bk = (const float*)d_in[4];
  const float* Wv = (const float*)d_in[5];
  const float* bv = (const float*)d_in[6];
  const float* Wo = (const float*)d_in[7];
  const float* bo = (const float*)d_in[8];
  const unsigned char* mask = (const unsigned char*)d_in[9];

  char* ws = (char*)d_ws;
  unsigned short* hs_bf = (unsigned short*)(ws);               // 8 MB
  unsigned short* Wq_bf = (unsigned short*)(ws + (8u << 20));  // 2 MB
  unsigned short* Wk_bf = (unsigned short*)(ws + (10u << 20));
  unsigned short* Wv_bf = (unsigned short*)(ws + (12u << 20));
  unsigned short* Wo_bf = (unsigned short*)(ws + (14u << 20));
  unsigned short* Qs    = (unsigned short*)(ws + (16u << 20)); // 8 MB (pre-scaled)
  unsigned short* Kbf   = (unsigned short*)(ws + (24u << 20)); // 8 MB
  unsigned short* VT    = (unsigned short*)(ws + (32u << 20)); // 8 MB  [b,h,d,s]
  unsigned short* ctxb  = (unsigned short*)(ws + (40u << 20)); // 8 MB
  float* out = (float*)d_out;

  cvt5_kernel<<<dim3(256, 5), 256, 0, stream>>>(hs, Wq, Wk, Wv, Wo,
                                                hs_bf, Wq_bf, Wk_bf, Wv_bf, Wo_bf);
  gemm_qkv<<<dim3(32, 8, 3), 256, 0, stream>>>(hs_bf, Wq_bf, Wk_bf, Wv_bf,
                                               bq, bk, bv, Qs, Kbf, VT);
  attn_kernel<<<dim3(32, 32), 256, 0, stream>>>(Qs, Kbf, VT, mask, ctxb);
  gemm_o<<<dim3(32, 8), 256, 0, stream>>>(ctxb, Wo_bf, bo, out);
}

// Round 2
// 163.343 us; speedup vs baseline: 2.2063x; 2.2063x over previous
//
#include <hip/hip_runtime.h>

typedef short bf16x8 __attribute__((ext_vector_type(8)));
typedef float f32x4 __attribute__((ext_vector_type(4)));
typedef unsigned short us4 __attribute__((ext_vector_type(4)));

#define S_LEN 2048
#define HIDD 1024
#define NH 16
#define HD 64
#define NEGV -1e9f

#define BM 128
#define BN 128
#define BK 64
#define LDSS 72  // 64 + 8 pad for GEMM LDS tiles

static __device__ __forceinline__ unsigned short f2bf(float f) {
  union { float f; unsigned u; } v; v.f = f;
  unsigned r = v.u + 0x7FFFu + ((v.u >> 16) & 1u);  // RNE
  return (unsigned short)(r >> 16);
}

#define GLD16(gp, lp)                                                        \
  __builtin_amdgcn_global_load_lds(                                         \
      (const __attribute__((address_space(1))) void*)(gp),                  \
      (__attribute__((address_space(3))) void*)(lp), 16, 0, 0)

// ---------------- f32 -> bf16 conversion for hs + 4 weights ----------------
__global__ __launch_bounds__(256) void cvt5_kernel(
    const float* __restrict__ s0, const float* __restrict__ s1, const float* __restrict__ s2,
    const float* __restrict__ s3, const float* __restrict__ s4,
    unsigned short* __restrict__ d0, unsigned short* __restrict__ d1,
    unsigned short* __restrict__ d2, unsigned short* __restrict__ d3,
    unsigned short* __restrict__ d4) {
  const float* s; unsigned short* d; int n4;
  switch (blockIdx.y) {
    case 0: s = s0; d = d0; n4 = (2 * S_LEN * HIDD) / 4; break;
    case 1: s = s1; d = d1; n4 = (HIDD * HIDD) / 4; break;
    case 2: s = s2; d = d2; n4 = (HIDD * HIDD) / 4; break;
    case 3: s = s3; d = d3; n4 = (HIDD * HIDD) / 4; break;
    default: s = s4; d = d4; n4 = (HIDD * HIDD) / 4; break;
  }
  for (int i = blockIdx.x * blockDim.x + threadIdx.x; i < n4;
       i += gridDim.x * blockDim.x) {
    float4 v = ((const float4*)s)[i];
    us4 o;
    o.x = f2bf(v.x); o.y = f2bf(v.y); o.z = f2bf(v.z); o.w = f2bf(v.w);
    ((us4*)d)[i] = o;
  }
}

// ---------------- mask -> bitmask [S][S/32] u32 ----------------
__global__ __launch_bounds__(256) void maskbits_kernel(
    const unsigned char* __restrict__ m8, unsigned* __restrict__ bits) {
  int idx = blockIdx.x * 256 + threadIdx.x;  // 2048*64 = 131072
  int q = idx >> 6, w = idx & 63;
  bool bytemode = (m8[1] != 0);
  unsigned r = 0;
  if (bytemode) {
    const uint4* p = (const uint4*)(m8 + (size_t)q * 2048 + w * 32);
    uint4 a = p[0], b = p[1];
    unsigned v[8] = {a.x, a.y, a.z, a.w, b.x, b.y, b.z, b.w};
#pragma unroll
    for (int j = 0; j < 8; ++j)
#pragma unroll
      for (int k = 0; k < 4; ++k)
        r |= (((v[j] >> (k * 8)) & 255u) ? 1u : 0u) << (j * 4 + k);
  } else {
    const int4* p = (const int4*)((const int*)m8 + (size_t)q * 2048 + (size_t)w * 32);
#pragma unroll
    for (int j = 0; j < 8; ++j) {
      int4 v = p[j];
      r |= (v.x ? 1u : 0u) << (j * 4 + 0);
      r |= (v.y ? 1u : 0u) << (j * 4 + 1);
      r |= (v.z ? 1u : 0u) << (j * 4 + 2);
      r |= (v.w ? 1u : 0u) << (j * 4 + 3);
    }
  }
  bits[idx] = r;
}

// ---------------- shared GEMM core: C = A[M,K] * W[N,K]^T ----------------
static __device__ __forceinline__ void gemm_core(
    const unsigned short* __restrict__ A, const unsigned short* __restrict__ W,
    int bm0, int bn0, unsigned short* As, unsigned short* Bs, f32x4 (&acc)[4][4]) {
  const int tid = threadIdx.x;
  const int lane = tid & 63;
  const int wid = tid >> 6;
  const int wr = wid >> 1, wc = wid & 1;
  const int l15 = lane & 15, g = lane >> 4;

  for (int k0 = 0; k0 < HIDD; k0 += BK) {
    __syncthreads();
#pragma unroll
    for (int it = 0; it < 4; ++it) {
      int id = tid + it * 256;
      int row = id >> 3;
      int col = (id & 7) * 8;
      *(bf16x8*)&As[row * LDSS + col] =
          *(const bf16x8*)&A[(size_t)(bm0 + row) * HIDD + k0 + col];
      *(bf16x8*)&Bs[row * LDSS + col] =
          *(const bf16x8*)&W[(size_t)(bn0 + row) * HIDD + k0 + col];
    }
    __syncthreads();
#pragma unroll
    for (int kk = 0; kk < 2; ++kk) {
      bf16x8 af[4], bfr[4];
#pragma unroll
      for (int m = 0; m < 4; ++m)
        af[m] = *(const bf16x8*)&As[(wr * 64 + m * 16 + l15) * LDSS + kk * 32 + g * 8];
#pragma unroll
      for (int n = 0; n < 4; ++n)
        bfr[n] = *(const bf16x8*)&Bs[(wc * 64 + n * 16 + l15) * LDSS + kk * 32 + g * 8];
#pragma unroll
      for (int m = 0; m < 4; ++m)
#pragma unroll
        for (int n = 0; n < 4; ++n)
          acc[m][n] = __builtin_amdgcn_mfma_f32_16x16x32_bf16(af[m], bfr[n], acc[m][n], 0, 0, 0);
    }
  }
}

// ---------------- QKV projection (z=0:Q scaled by log2e/8, 1:K, 2:V->VT) ---
__global__ __launch_bounds__(256) void gemm_qkv(
    const unsigned short* __restrict__ hs,
    const unsigned short* __restrict__ Wq, const unsigned short* __restrict__ Wk,
    const unsigned short* __restrict__ Wv,
    const float* __restrict__ bq, const float* __restrict__ bk, const float* __restrict__ bv,
    unsigned short* __restrict__ Qs, unsigned short* __restrict__ Kb,
    unsigned short* __restrict__ VT) {
  __shared__ unsigned short As[BM * LDSS];
  __shared__ unsigned short Bs[BN * LDSS];
  const int z = blockIdx.z;
  const unsigned short* W = (z == 0) ? Wq : ((z == 1) ? Wk : Wv);
  const float* bias = (z == 0) ? bq : ((z == 1) ? bk : bv);

  f32x4 acc[4][4];
#pragma unroll
  for (int m = 0; m < 4; ++m)
#pragma unroll
    for (int n = 0; n < 4; ++n) acc[m][n] = (f32x4){0.f, 0.f, 0.f, 0.f};

  const int bm0 = blockIdx.x * BM, bn0 = blockIdx.y * BN;
  gemm_core(hs, W, bm0, bn0, As, Bs, acc);

  const int lane = threadIdx.x & 63;
  const int wid = threadIdx.x >> 6;
  const int wr = wid >> 1, wc = wid & 1;
  const int l15 = lane & 15, g = lane >> 4;
  const float qscale = 0.125f * 1.44269504088896f;  // 1/sqrt(64) * log2(e)

#pragma unroll
  for (int m = 0; m < 4; ++m) {
#pragma unroll
    for (int n = 0; n < 4; ++n) {
      int grow0 = bm0 + wr * 64 + m * 16 + g * 4;
      int gcol = bn0 + wc * 64 + n * 16 + l15;
      float bv_ = bias[gcol];
      if (z == 0) {
#pragma unroll
        for (int i = 0; i < 4; ++i)
          Qs[(size_t)(grow0 + i) * HIDD + gcol] = f2bf((acc[m][n][i] + bv_) * qscale);
      } else if (z == 1) {
#pragma unroll
        for (int i = 0; i < 4; ++i)
          Kb[(size_t)(grow0 + i) * HIDD + gcol] = f2bf(acc[m][n][i] + bv_);
      } else {
        int b = grow0 >> 11, s = grow0 & 2047;
        int h = gcol >> 6, d = gcol & 63;
        us4 pk;
#pragma unroll
        for (int i = 0; i < 4; ++i) pk[i] = f2bf(acc[m][n][i] + bv_);
        *(us4*)&VT[((size_t)(b * NH + h) * HD + d) * S_LEN + s] = pk;
      }
    }
  }
}

// ---------------- output projection: f32 result ----------------
__global__ __launch_bounds__(256) void gemm_o(
    const unsigned short* __restrict__ ctx, const unsigned short* __restrict__ Wo,
    const float* __restrict__ bo, float* __restrict__ out) {
  __shared__ unsigned short As[BM * LDSS];
  __shared__ unsigned short Bs[BN * LDSS];
  f32x4 acc[4][4];
#pragma unroll
  for (int m = 0; m < 4; ++m)
#pragma unroll
    for (int n = 0; n < 4; ++n) acc[m][n] = (f32x4){0.f, 0.f, 0.f, 0.f};

  const int bm0 = blockIdx.x * BM, bn0 = blockIdx.y * BN;
  gemm_core(ctx, Wo, bm0, bn0, As, Bs, acc);

  const int lane = threadIdx.x & 63;
  const int wid = threadIdx.x >> 6;
  const int wr = wid >> 1, wc = wid & 1;
  const int l15 = lane & 15, g = lane >> 4;
#pragma unroll
  for (int m = 0; m < 4; ++m) {
#pragma unroll
    for (int n = 0; n < 4; ++n) {
      int grow0 = bm0 + wr * 64 + m * 16 + g * 4;
      int gcol = bn0 + wc * 64 + n * 16 + l15;
      float bv_ = bo[gcol];
#pragma unroll
      for (int i = 0; i < 4; ++i)
        out[(size_t)(grow0 + i) * HIDD + gcol] = acc[m][n][i] + bv_;
    }
  }
}

// ---------------- flash attention v2 ----------------
// grid (bh=32, qblk=16), 512 thr / 8 waves; wave = 16 q rows; KVBLK=64 dbuf LDS.
// K/V tiles: linear LDS [64 rows][8 chunks of 16B], source pre-permuted with
// ch ^= (row&7) (XOR involution); reads apply same XOR -> conflict-free b128.
__global__ __launch_bounds__(512) void attn2_kernel(
    const unsigned short* __restrict__ Qs, const unsigned short* __restrict__ Kb,
    const unsigned short* __restrict__ VT, const unsigned* __restrict__ mbits,
    unsigned short* __restrict__ ctx) {
  __shared__ __align__(16) unsigned short Kt[2][4096];  // [buf][row*64 + ch*8]
  __shared__ __align__(16) unsigned short Vt[2][4096];
  __shared__ __align__(16) unsigned short Pl[8][16][72];

  const int tid = threadIdx.x;
  const int wid = tid >> 6, lane = tid & 63;
  const int l15 = lane & 15, g = lane >> 4;
  const int l7 = l15 & 7;
  const int b = blockIdx.x >> 4, h = blockIdx.x & 15;
  const int qrow = blockIdx.y * 128 + wid * 16 + l15;

  const unsigned short* Kbh = Kb + (size_t)b * S_LEN * HIDD + h * HD;
  const unsigned short* VTbh = VT + (size_t)(b * NH + h) * HD * S_LEN;

  // Q B-frags (pre-scaled by log2e/8 in gemm_qkv)
  const unsigned short* Qrow = Qs + (size_t)(b * S_LEN + qrow) * HIDD + h * HD;
  bf16x8 qf0 = *(const bf16x8*)(Qrow + g * 8);
  bf16x8 qf1 = *(const bf16x8*)(Qrow + 32 + g * 8);

  const unsigned* mrow = mbits + (size_t)qrow * 64;

  // swizzled per-lane LDS read bases (shorts): row l15 (+16t via imm), chunk (kk*4+g)^l7
  const int rb0 = l15 * 64 + ((g ^ l7)) * 8;
  const int rb1 = l15 * 64 + ((g ^ l7) ^ 4) * 8;

  // staging: waves 0-3 stage K, 4-7 stage V; 2 issues each; 64 granules/issue.
  // granule p = ibase + lane; r = p>>3 (row), chp = p&7 (lds chunk),
  // source chunk = chp ^ (r&7)  -> each 8-lane group reads one full 128B row.
  const int wk = wid & 3;

  float m_run = -1e8f, l_run = 0.f;
  f32x4 oacc[4];
#pragma unroll
  for (int dc = 0; dc < 4; ++dc) oacc[dc] = (f32x4){0.f, 0.f, 0.f, 0.f};

#define STAGE(bufi, kv0_)                                                     \
  do {                                                                        \
    _Pragma("unroll")                                                         \
    for (int j = 0; j < 2; ++j) {                                             \
      int p = (wk * 2 + j) * 64 + lane;                                       \
      int r_ = p >> 3;                                                        \
      int ch_ = (p & 7) ^ (r_ & 7);                                           \
      if (wid < 4)                                                            \
        GLD16(Kbh + (size_t)((kv0_) + r_) * HIDD + ch_ * 8,                   \
              &Kt[bufi][(wk * 2 + j) * 512]);                                 \
      else                                                                    \
        GLD16(VTbh + (size_t)r_ * S_LEN + (kv0_) + ch_ * 8,                   \
              &Vt[bufi][(wk * 2 + j) * 512]);                                 \
    }                                                                         \
  } while (0)

  uint2 mw = *(const uint2*)mrow;
  STAGE(0, 0);
  __syncthreads();

  for (int it = 0; it < 32; ++it) {
    const int buf = it & 1;
    uint2 mw_n = mw;
    if (it + 1 < 32) {
      STAGE(buf ^ 1, (it + 1) * 64);
      mw_n = *(const uint2*)(mrow + (it + 1) * 2);
    }

    // S^T tiles: sacc[t] = K(rows t*16..+15) x Q^T, k over d=64
    const unsigned short* Kbuf = &Kt[buf][0];
    f32x4 sacc[4];
#pragma unroll
    for (int t = 0; t < 4; ++t) {
      sacc[t] = (f32x4){0.f, 0.f, 0.f, 0.f};
      bf16x8 ka = *(const bf16x8*)(Kbuf + t * 1024 + rb0);
      bf16x8 kb2 = *(const bf16x8*)(Kbuf + t * 1024 + rb1);
      sacc[t] = __builtin_amdgcn_mfma_f32_16x16x32_bf16(ka, qf0, sacc[t], 0, 0, 0);
      sacc[t] = __builtin_amdgcn_mfma_f32_16x16x32_bf16(kb2, qf1, sacc[t], 0, 0, 0);
    }

    // mask (bit kv_local = t*16 + g*4 + i) + max
    float pmax = NEGV;
#pragma unroll
    for (int t = 0; t < 4; ++t) {
      unsigned word = (t & 2) ? mw.y : mw.x;
      unsigned nib = (word >> ((t & 1) * 16 + g * 4)) & 0xFu;
#pragma unroll
      for (int i = 0; i < 4; ++i) {
        sacc[t][i] = ((nib >> i) & 1u) ? sacc[t][i] : NEGV;
        pmax = fmaxf(pmax, sacc[t][i]);
      }
    }
    pmax = fmaxf(pmax, __shfl_xor(pmax, 16));
    pmax = fmaxf(pmax, __shfl_xor(pmax, 32));
    float m_new = fmaxf(m_run, pmax);
    float corr = exp2f(m_run - m_new);
    float lsum = 0.f;
#pragma unroll
    for (int t = 0; t < 4; ++t) {
      us4 pk;
#pragma unroll
      for (int i = 0; i < 4; ++i) {
        float p = exp2f(sacc[t][i] - m_new);
        lsum += p;
        pk[i] = f2bf(p);
      }
      *(us4*)&Pl[wid][l15][t * 16 + g * 4] = pk;
    }
    lsum += __shfl_xor(lsum, 16);
    lsum += __shfl_xor(lsum, 32);
    l_run = l_run * corr + lsum;
    m_run = m_new;
#pragma unroll
    for (int dc = 0; dc < 4; ++dc) oacc[dc] *= corr;

    // P B-frags (same-wave LDS, compiler inserts lgkmcnt)
    bf16x8 pf0 = *(const bf16x8*)&Pl[wid][l15][g * 8];
    bf16x8 pf1 = *(const bf16x8*)&Pl[wid][l15][32 + g * 8];

    // O^T += VT_tile x P
    const unsigned short* Vbuf = &Vt[buf][0];
#pragma unroll
    for (int dc = 0; dc < 4; ++dc) {
      bf16x8 va = *(const bf16x8*)(Vbuf + dc * 1024 + rb0);
      bf16x8 vb = *(const bf16x8*)(Vbuf + dc * 1024 + rb1);
      oacc[dc] = __builtin_amdgcn_mfma_f32_16x16x32_bf16(va, pf0, oacc[dc], 0, 0, 0);
      oacc[dc] = __builtin_amdgcn_mfma_f32_16x16x32_bf16(vb, pf1, oacc[dc], 0, 0, 0);
    }

    mw = mw_n;
    __syncthreads();  // drains vmcnt (staged tiles landed) + buffer handoff
  }

  float inv_l = 1.f / l_run;
  unsigned short* crow = ctx + (size_t)(b * S_LEN + qrow) * HIDD + h * HD;
#pragma unroll
  for (int dc = 0; dc < 4; ++dc) {
    us4 o;
#pragma unroll
    for (int i = 0; i < 4; ++i) o[i] = f2bf(oacc[dc][i] * inv_l);
    *(us4*)&crow[dc * 16 + g * 4] = o;
  }
}

extern "C" void kernel_launch(void* const* d_in, const int* in_sizes, int n_in,
                              void* d_out, int out_size, void* d_ws, size_t ws_size,
                              hipStream_t stream) {
  const float* hs = (const float*)d_in[0];
  const float* Wq = (const float*)d_in[1];
  const float* bq = (const float*)d_in[2];
  const float* Wk = (const float*)d_in[3];
  const float* bk = (const float*)d_in[4];
  const float* Wv = (const float*)d_in[5];
  const float* bv = (const float*)d_in[6];
  const float* Wo = (const float*)d_in[7];
  const float* bo = (const float*)d_in[8];
  const unsigned char* mask = (const unsigned char*)d_in[9];

  char* ws = (char*)d_ws;
  unsigned short* hs_bf = (unsigned short*)(ws);               // 8 MB (dead after gemm_qkv)
  unsigned short* Wq_bf = (unsigned short*)(ws + (8u << 20));  // 2 MB
  unsigned short* Wk_bf = (unsigned short*)(ws + (10u << 20));
  unsigned short* Wv_bf = (unsigned short*)(ws + (12u << 20));
  unsigned short* Wo_bf = (unsigned short*)(ws + (14u << 20));
  unsigned short* Qs    = (unsigned short*)(ws + (16u << 20)); // 8 MB (pre-scaled, log2e)
  unsigned short* Kbf   = (unsigned short*)(ws + (24u << 20)); // 8 MB
  unsigned short* VT    = (unsigned short*)(ws + (32u << 20)); // 8 MB [b,h,d,s]
  unsigned short* ctxb  = (unsigned short*)(ws + (40u << 20)); // 8 MB
  unsigned* mbits = (unsigned*)(ws);  // 512 KB, overwrites hs_bf AFTER gemm_qkv
  float* out = (float*)d_out;

  cvt5_kernel<<<dim3(256, 5), 256, 0, stream>>>(hs, Wq, Wk, Wv, Wo,
                                                hs_bf, Wq_bf, Wk_bf, Wv_bf, Wo_bf);
  gemm_qkv<<<dim3(32, 8, 3), 256, 0, stream>>>(hs_bf, Wq_bf, Wk_bf, Wv_bf,
                                               bq, bk, bv, Qs, Kbf, VT);
  maskbits_kernel<<<512, 256, 0, stream>>>(mask, mbits);
  attn2_kernel<<<dim3(32, 16), 512, 0, stream>>>(Qs, Kbf, VT, mbits, ctxb);
  gemm_o<<<dim3(32, 8), 256, 0, stream>>>(ctxb, Wo_bf, bo, out);
}

// Round 3
// 139.902 us; speedup vs baseline: 2.5760x; 1.1676x over previous
//
#include <hip/hip_runtime.h>

typedef short bf16x8 __attribute__((ext_vector_type(8)));
typedef float f32x4 __attribute__((ext_vector_type(4)));
typedef unsigned short us4 __attribute__((ext_vector_type(4)));

#define S_LEN 2048
#define HIDD 1024
#define NH 16
#define HD 64

#define BK 64

static __device__ __forceinline__ unsigned short f2bf(float f) {
  union { float f; unsigned u; } v; v.f = f;
  unsigned r = v.u + 0x7FFFu + ((v.u >> 16) & 1u);  // RNE
  return (unsigned short)(r >> 16);
}

static __device__ __forceinline__ unsigned cvtpk(float lo, float hi) {
  unsigned r;
  asm("v_cvt_pk_bf16_f32 %0, %1, %2" : "=v"(r) : "v"(lo), "v"(hi));
  return r;
}

#define GLD16(gp, lp)                                                        \
  __builtin_amdgcn_global_load_lds(                                         \
      (const __attribute__((address_space(1))) void*)(gp),                  \
      (__attribute__((address_space(3))) void*)(lp), 16, 0, 0)

// ---------------- f32 -> bf16 conversion for hs + 4 weights ----------------
__global__ __launch_bounds__(256) void cvt5_kernel(
    const float* __restrict__ s0, const float* __restrict__ s1, const float* __restrict__ s2,
    const float* __restrict__ s3, const float* __restrict__ s4,
    unsigned short* __restrict__ d0, unsigned short* __restrict__ d1,
    unsigned short* __restrict__ d2, unsigned short* __restrict__ d3,
    unsigned short* __restrict__ d4) {
  const float* s; unsigned short* d; int n4;
  switch (blockIdx.y) {
    case 0: s = s0; d = d0; n4 = (2 * S_LEN * HIDD) / 4; break;
    case 1: s = s1; d = d1; n4 = (HIDD * HIDD) / 4; break;
    case 2: s = s2; d = d2; n4 = (HIDD * HIDD) / 4; break;
    case 3: s = s3; d = d3; n4 = (HIDD * HIDD) / 4; break;
    default: s = s4; d = d4; n4 = (HIDD * HIDD) / 4; break;
  }
  for (int i = blockIdx.x * blockDim.x + threadIdx.x; i < n4;
       i += gridDim.x * blockDim.x) {
    float4 v = ((const float4*)s)[i];
    us4 o;
    o.x = f2bf(v.x); o.y = f2bf(v.y); o.z = f2bf(v.z); o.w = f2bf(v.w);
    ((us4*)d)[i] = o;
  }
}

// ---------------- mask -> bitmask [S][S/32] u32 ----------------
__global__ __launch_bounds__(256) void maskbits_kernel(
    const unsigned char* __restrict__ m8, unsigned* __restrict__ bits) {
  int idx = blockIdx.x * 256 + threadIdx.x;  // 2048*64 = 131072
  int q = idx >> 6, w = idx & 63;
  bool bytemode = (m8[1] != 0);
  unsigned r = 0;
  if (bytemode) {
    const uint4* p = (const uint4*)(m8 + (size_t)q * 2048 + w * 32);
    uint4 a = p[0], b = p[1];
    unsigned v[8] = {a.x, a.y, a.z, a.w, b.x, b.y, b.z, b.w};
#pragma unroll
    for (int j = 0; j < 8; ++j)
#pragma unroll
      for (int k = 0; k < 4; ++k)
        r |= (((v[j] >> (k * 8)) & 255u) ? 1u : 0u) << (j * 4 + k);
  } else {
    const int4* p = (const int4*)((const int*)m8 + (size_t)q * 2048 + (size_t)w * 32);
#pragma unroll
    for (int j = 0; j < 8; ++j) {
      int4 v = p[j];
      r |= (v.x ? 1u : 0u) << (j * 4 + 0);
      r |= (v.y ? 1u : 0u) << (j * 4 + 1);
      r |= (v.z ? 1u : 0u) << (j * 4 + 2);
      r |= (v.w ? 1u : 0u) << (j * 4 + 3);
    }
  }
  bits[idx] = r;
}

// ---------------- GEMM core v2: GLD16 staging + XOR-chunk swizzle ----------
// C = A[M,K] * W[N,K]^T. Tile BM x 128 (BM = MFRAG*32), BK=64, 4 waves (2x2).
// LDS linear [row][ch*8] shorts; global src chunk = ch ^ (row&7) (involution);
// reads apply same XOR -> conflict-free ds_read_b128, coalesced 128B src rows.
template <int MFRAG>
static __device__ __forceinline__ void gemm_core2(
    const unsigned short* __restrict__ A, const unsigned short* __restrict__ W,
    int bm0, int bn0, unsigned short* As, unsigned short* Bs,
    f32x4 (&acc)[MFRAG][4]) {
  const int tid = threadIdx.x;
  const int lane = tid & 63;
  const int wid = tid >> 6;
  const int wr = wid >> 1, wc = wid & 1;
  const int l15 = lane & 15, g = lane >> 4, l7 = l15 & 7;
  const int ra = (g ^ l7) * 8;  // kk=0 chunk offset (shorts); kk=1 -> ^32

  for (int k0 = 0; k0 < HIDD; k0 += BK) {
    __syncthreads();
#pragma unroll
    for (int it = 0; it < MFRAG; ++it) {
      int p = it * 256 + tid;
      int r = p >> 3, ch = (p & 7) ^ (r & 7);
      GLD16(A + (size_t)(bm0 + r) * HIDD + k0 + ch * 8,
            As + (it * 256 + wid * 64) * 8);
    }
#pragma unroll
    for (int it = 0; it < 4; ++it) {
      int p = it * 256 + tid;
      int r = p >> 3, ch = (p & 7) ^ (r & 7);
      GLD16(W + (size_t)(bn0 + r) * HIDD + k0 + ch * 8,
            Bs + (it * 256 + wid * 64) * 8);
    }
    __syncthreads();
#pragma unroll
    for (int kk = 0; kk < 2; ++kk) {
      bf16x8 af[MFRAG], bfr[4];
#pragma unroll
      for (int m = 0; m < MFRAG; ++m)
        af[m] = *(const bf16x8*)&As[(wr * (MFRAG * 16) + m * 16 + l15) * 64 + (ra ^ (kk * 32))];
#pragma unroll
      for (int n = 0; n < 4; ++n)
        bfr[n] = *(const bf16x8*)&Bs[(wc * 64 + n * 16 + l15) * 64 + (ra ^ (kk * 32))];
#pragma unroll
      for (int m = 0; m < MFRAG; ++m)
#pragma unroll
        for (int n = 0; n < 4; ++n)
          acc[m][n] = __builtin_amdgcn_mfma_f32_16x16x32_bf16(af[m], bfr[n], acc[m][n], 0, 0, 0);
    }
  }
}

// ---------------- QKV projection (z=0:Q scaled 1/8, 1:K, 2:V->VT) ----------
__global__ __launch_bounds__(256) void gemm_qkv(
    const unsigned short* __restrict__ hs,
    const unsigned short* __restrict__ Wq, const unsigned short* __restrict__ Wk,
    const unsigned short* __restrict__ Wv,
    const float* __restrict__ bq, const float* __restrict__ bk, const float* __restrict__ bv,
    unsigned short* __restrict__ Qs, unsigned short* __restrict__ Kb,
    unsigned short* __restrict__ VT) {
  __shared__ __align__(16) unsigned short As[128 * 64];
  __shared__ __align__(16) unsigned short Bs[128 * 64];
  const int z = blockIdx.z;
  const unsigned short* W = (z == 0) ? Wq : ((z == 1) ? Wk : Wv);
  const float* bias = (z == 0) ? bq : ((z == 1) ? bk : bv);

  f32x4 acc[4][4];
#pragma unroll
  for (int m = 0; m < 4; ++m)
#pragma unroll
    for (int n = 0; n < 4; ++n) acc[m][n] = (f32x4){0.f, 0.f, 0.f, 0.f};

  const int bm0 = blockIdx.x * 128, bn0 = blockIdx.y * 128;
  gemm_core2<4>(hs, W, bm0, bn0, As, Bs, acc);

  const int lane = threadIdx.x & 63;
  const int wid = threadIdx.x >> 6;
  const int wr = wid >> 1, wc = wid & 1;
  const int l15 = lane & 15, g = lane >> 4;
  const float qscale = 0.125f;  // 1/sqrt(64); nat-log softmax downstream

#pragma unroll
  for (int m = 0; m < 4; ++m) {
#pragma unroll
    for (int n = 0; n < 4; ++n) {
      int grow0 = bm0 + wr * 64 + m * 16 + g * 4;
      int gcol = bn0 + wc * 64 + n * 16 + l15;
      float bv_ = bias[gcol];
      if (z == 0) {
#pragma unroll
        for (int i = 0; i < 4; ++i)
          Qs[(size_t)(grow0 + i) * HIDD + gcol] = f2bf((acc[m][n][i] + bv_) * qscale);
      } else if (z == 1) {
#pragma unroll
        for (int i = 0; i < 4; ++i)
          Kb[(size_t)(grow0 + i) * HIDD + gcol] = f2bf(acc[m][n][i] + bv_);
      } else {
        int b = grow0 >> 11, s = grow0 & 2047;
        int h = gcol >> 6, d = gcol & 63;
        us4 pk;
#pragma unroll
        for (int i = 0; i < 4; ++i) pk[i] = f2bf(acc[m][n][i] + bv_);
        *(us4*)&VT[((size_t)(b * NH + h) * HD + d) * S_LEN + s] = pk;
      }
    }
  }
}

// ---------------- output projection: f32 result, BM=64 (512 blocks) --------
__global__ __launch_bounds__(256) void gemm_o(
    const unsigned short* __restrict__ ctx, const unsigned short* __restrict__ Wo,
    const float* __restrict__ bo, float* __restrict__ out) {
  __shared__ __align__(16) unsigned short As[64 * 64];
  __shared__ __align__(16) unsigned short Bs[128 * 64];
  f32x4 acc[2][4];
#pragma unroll
  for (int m = 0; m < 2; ++m)
#pragma unroll
    for (int n = 0; n < 4; ++n) acc[m][n] = (f32x4){0.f, 0.f, 0.f, 0.f};

  const int bm0 = blockIdx.x * 64, bn0 = blockIdx.y * 128;
  gemm_core2<2>(ctx, Wo, bm0, bn0, As, Bs, acc);

  const int lane = threadIdx.x & 63;
  const int wid = threadIdx.x >> 6;
  const int wr = wid >> 1, wc = wid & 1;
  const int l15 = lane & 15, g = lane >> 4;
#pragma unroll
  for (int m = 0; m < 2; ++m) {
#pragma unroll
    for (int n = 0; n < 4; ++n) {
      int grow0 = bm0 + wr * 32 + m * 16 + g * 4;
      int gcol = bn0 + wc * 64 + n * 16 + l15;
      float bv_ = bo[gcol];
#pragma unroll
      for (int i = 0; i < 4; ++i)
        out[(size_t)(grow0 + i) * HIDD + gcol] = acc[m][n][i] + bv_;
    }
  }
}

// ---------------- flash attention v3 ----------------
// grid (bh=32, qblk=16), 512 thr / 8 waves; wave = 16 q rows; KVBLK=64 dbuf.
// Softmax: unmasked running max (exact: scales num+den identically),
// defer-max THR=8*ln2, native __expf, cvt_pk packing, mask applied post-exp.
__global__ __launch_bounds__(512) void attn3_kernel(
    const unsigned short* __restrict__ Qs, const unsigned short* __restrict__ Kb,
    const unsigned short* __restrict__ VT, const unsigned* __restrict__ mbits,
    unsigned short* __restrict__ ctx) {
  __shared__ __align__(16) unsigned short Kt[2][4096];  // [buf][row*64 + ch*8]
  __shared__ __align__(16) unsigned short Vt[2][4096];
  __shared__ __align__(16) unsigned short Pl[8][16][72];

  const int tid = threadIdx.x;
  const int wid = tid >> 6, lane = tid & 63;
  const int l15 = lane & 15, g = lane >> 4;
  const int l7 = l15 & 7;
  const int b = blockIdx.x >> 4, h = blockIdx.x & 15;
  const int qrow = blockIdx.y * 128 + wid * 16 + l15;

  const unsigned short* Kbh = Kb + (size_t)b * S_LEN * HIDD + h * HD;
  const unsigned short* VTbh = VT + (size_t)(b * NH + h) * HD * S_LEN;

  const unsigned short* Qrow = Qs + (size_t)(b * S_LEN + qrow) * HIDD + h * HD;
  bf16x8 qf0 = *(const bf16x8*)(Qrow + g * 8);
  bf16x8 qf1 = *(const bf16x8*)(Qrow + 32 + g * 8);

  const unsigned* mrow = mbits + (size_t)qrow * 64;

  const int rb0 = l15 * 64 + ((g ^ l7)) * 8;
  const int rb1 = l15 * 64 + ((g ^ l7) ^ 4) * 8;
  const int wk = wid & 3;

  float m_run = -1e8f, l_run = 0.f;
  f32x4 oacc[4];
#pragma unroll
  for (int dc = 0; dc < 4; ++dc) oacc[dc] = (f32x4){0.f, 0.f, 0.f, 0.f};

#define STAGE(bufi, kv0_)                                                     \
  do {                                                                        \
    _Pragma("unroll")                                                         \
    for (int j = 0; j < 2; ++j) {                                             \
      int p = (wk * 2 + j) * 64 + lane;                                       \
      int r_ = p >> 3;                                                        \
      int ch_ = (p & 7) ^ (r_ & 7);                                           \
      if (wid < 4)                                                            \
        GLD16(Kbh + (size_t)((kv0_) + r_) * HIDD + ch_ * 8,                   \
              &Kt[bufi][(wk * 2 + j) * 512]);                                 \
      else                                                                    \
        GLD16(VTbh + (size_t)r_ * S_LEN + (kv0_) + ch_ * 8,                   \
              &Vt[bufi][(wk * 2 + j) * 512]);                                 \
    }                                                                         \
  } while (0)

  uint2 mw = *(const uint2*)mrow;
  STAGE(0, 0);
  __syncthreads();

  for (int it = 0; it < 32; ++it) {
    const int buf = it & 1;
    uint2 mw_n = mw;
    if (it + 1 < 32) {
      STAGE(buf ^ 1, (it + 1) * 64);
      mw_n = *(const uint2*)(mrow + (it + 1) * 2);
    }

    // S^T tiles (raw, unmasked)
    const unsigned short* Kbuf = &Kt[buf][0];
    f32x4 sacc[4];
#pragma unroll
    for (int t = 0; t < 4; ++t) {
      sacc[t] = (f32x4){0.f, 0.f, 0.f, 0.f};
      bf16x8 ka = *(const bf16x8*)(Kbuf + t * 1024 + rb0);
      bf16x8 kb2 = *(const bf16x8*)(Kbuf + t * 1024 + rb1);
      sacc[t] = __builtin_amdgcn_mfma_f32_16x16x32_bf16(ka, qf0, sacc[t], 0, 0, 0);
      sacc[t] = __builtin_amdgcn_mfma_f32_16x16x32_bf16(kb2, qf1, sacc[t], 0, 0, 0);
    }

    // raw column max (no mask needed: common rescale cancels in O/l)
    float pmax = sacc[0][0];
#pragma unroll
    for (int t = 0; t < 4; ++t)
#pragma unroll
      for (int i = 0; i < 4; ++i) pmax = fmaxf(pmax, sacc[t][i]);
    pmax = fmaxf(pmax, __shfl_xor(pmax, 16));
    pmax = fmaxf(pmax, __shfl_xor(pmax, 32));

    // defer-max: rescale only when max grew past THR (wave-uniform branch)
    if (__any(pmax > m_run + 5.545177f)) {   // 8*ln2
      float m_new = fmaxf(m_run, pmax);
      float corr = __expf(m_run - m_new);
      l_run *= corr;
#pragma unroll
      for (int dc = 0; dc < 4; ++dc) oacc[dc] *= corr;
      m_run = m_new;
    }

    float lsum = 0.f;
#pragma unroll
    for (int t = 0; t < 4; ++t) {
      unsigned word = (t & 2) ? mw.y : mw.x;
      unsigned nib = (word >> ((t & 1) * 16 + g * 4)) & 0xFu;
      float pm[4];
#pragma unroll
      for (int i = 0; i < 4; ++i) {
        float p = __expf(sacc[t][i] - m_run);
        pm[i] = ((nib >> i) & 1u) ? p : 0.f;
        lsum += pm[i];
      }
      uint2 w2;
      w2.x = cvtpk(pm[0], pm[1]);
      w2.y = cvtpk(pm[2], pm[3]);
      *(uint2*)&Pl[wid][l15][t * 16 + g * 4] = w2;
    }
    lsum += __shfl_xor(lsum, 16);
    lsum += __shfl_xor(lsum, 32);
    l_run += lsum;

    bf16x8 pf0 = *(const bf16x8*)&Pl[wid][l15][g * 8];
    bf16x8 pf1 = *(const bf16x8*)&Pl[wid][l15][32 + g * 8];

    const unsigned short* Vbuf = &Vt[buf][0];
#pragma unroll
    for (int dc = 0; dc < 4; ++dc) {
      bf16x8 va = *(const bf16x8*)(Vbuf + dc * 1024 + rb0);
      bf16x8 vb = *(const bf16x8*)(Vbuf + dc * 1024 + rb1);
      oacc[dc] = __builtin_amdgcn_mfma_f32_16x16x32_bf16(va, pf0, oacc[dc], 0, 0, 0);
      oacc[dc] = __builtin_amdgcn_mfma_f32_16x16x32_bf16(vb, pf1, oacc[dc], 0, 0, 0);
    }

    mw = mw_n;
    __syncthreads();
  }

  float inv_l = 1.f / l_run;
  unsigned short* crow = ctx + (size_t)(b * S_LEN + qrow) * HIDD + h * HD;
#pragma unroll
  for (int dc = 0; dc < 4; ++dc) {
    us4 o;
#pragma unroll
    for (int i = 0; i < 4; ++i) o[i] = f2bf(oacc[dc][i] * inv_l);
    *(us4*)&crow[dc * 16 + g * 4] = o;
  }
}

extern "C" void kernel_launch(void* const* d_in, const int* in_sizes, int n_in,
                              void* d_out, int out_size, void* d_ws, size_t ws_size,
                              hipStream_t stream) {
  const float* hs = (const float*)d_in[0];
  const float* Wq = (const float*)d_in[1];
  const float* bq = (const float*)d_in[2];
  const float* Wk = (const float*)d_in[3];
  const float* bk = (const float*)d_in[4];
  const float* Wv = (const float*)d_in[5];
  const float* bv = (const float*)d_in[6];
  const float* Wo = (const float*)d_in[7];
  const float* bo = (const float*)d_in[8];
  const unsigned char* mask = (const unsigned char*)d_in[9];

  char* ws = (char*)d_ws;
  unsigned short* hs_bf = (unsigned short*)(ws);               // 8 MB (dead after gemm_qkv)
  unsigned short* Wq_bf = (unsigned short*)(ws + (8u << 20));  // 2 MB
  unsigned short* Wk_bf = (unsigned short*)(ws + (10u << 20));
  unsigned short* Wv_bf = (unsigned short*)(ws + (12u << 20));
  unsigned short* Wo_bf = (unsigned short*)(ws + (14u << 20));
  unsigned short* Qs    = (unsigned short*)(ws + (16u << 20)); // 8 MB (pre-scaled 1/8)
  unsigned short* Kbf   = (unsigned short*)(ws + (24u << 20)); // 8 MB
  unsigned short* VT    = (unsigned short*)(ws + (32u << 20)); // 8 MB [b,h,d,s]
  unsigned short* ctxb  = (unsigned short*)(ws + (40u << 20)); // 8 MB
  unsigned* mbits = (unsigned*)(ws);  // 512 KB, overwrites hs_bf AFTER gemm_qkv
  float* out = (float*)d_out;

  cvt5_kernel<<<dim3(256, 5), 256, 0, stream>>>(hs, Wq, Wk, Wv, Wo,
                                                hs_bf, Wq_bf, Wk_bf, Wv_bf, Wo_bf);
  gemm_qkv<<<dim3(32, 8, 3), 256, 0, stream>>>(hs_bf, Wq_bf, Wk_bf, Wv_bf,
                                               bq, bk, bv, Qs, Kbf, VT);
  maskbits_kernel<<<512, 256, 0, stream>>>(mask, mbits);
  attn3_kernel<<<dim3(32, 16), 512, 0, stream>>>(Qs, Kbf, VT, mbits, ctxb);
  gemm_o<<<dim3(64, 8), 256, 0, stream>>>(ctxb, Wo_bf, bo, out);
}